// Round 7
// baseline (95.369 us; speedup 1.0000x reference)
//
#include <hip/hip_runtime.h>
#include <math.h>

#define GDIM 256                 // grid cells per axis
#define NCELL (GDIM * GDIM)      // 65536
#define CELL 0.5f
#define INV_CELL 2.0f
#define ORIGIN (-64.0f)          // box [-64,64)^2; data |coord| <~ 41
#define BIGV 1e10f
#define EPSV 1e-8f

__device__ __forceinline__ void cell_xy(float x, float y, int& cx, int& cy) {
    cx = (int)floorf((x - ORIGIN) * INV_CELL);
    cy = (int)floorf((y - ORIGIN) * INV_CELL);
    cx = min(max(cx, 0), GDIM - 1);
    cy = min(max(cy, 0), GDIM - 1);
}

// A: sq (exact reference rounding) + cell histogram
__global__ void k_hist(const float2* __restrict__ pc, float* __restrict__ sq,
                       int* __restrict__ cellOf, int* __restrict__ rank,
                       unsigned* __restrict__ cnt, int n) {
#pragma clang fp contract(off)
    int i = blockIdx.x * blockDim.x + threadIdx.x;
    if (i >= n) return;
    float2 p = pc[i];
    float xx = p.x * p.x;
    float yy = p.y * p.y;
    sq[i] = xx + yy;
    int cx, cy; cell_xy(p.x, p.y, cx, cy);
    int c = (cy << 8) | cx;
    cellOf[i] = c;
    rank[i] = (int)atomicAdd(&cnt[c], 1u);
}

// S1: per-256-cell-chunk exclusive scan of cnt IN PLACE; chunk totals -> sums
// (chunk index == row cy, since cell = cy*256+cx)
__global__ void k_scan1(unsigned* __restrict__ cnt, unsigned* __restrict__ sums) {
    __shared__ unsigned tmp[256];
    const int t = threadIdx.x, b = blockIdx.x;
    unsigned v = cnt[b * 256 + t];
    tmp[t] = v; __syncthreads();
    for (int o = 1; o < 256; o <<= 1) {          // Hillis-Steele inclusive
        unsigned add = (t >= o) ? tmp[t - o] : 0u;
        __syncthreads();
        tmp[t] += add;
        __syncthreads();
    }
    cnt[b * 256 + t] = tmp[t] - v;               // exclusive within chunk
    if (t == 255) sums[b] = tmp[t];
}

// S2: exclusive scan of 256 chunk sums -> off[0..256]
__global__ void k_scan2(const unsigned* __restrict__ sums, unsigned* __restrict__ off) {
    __shared__ unsigned tmp[256];
    const int t = threadIdx.x;
    unsigned v = sums[t];
    tmp[t] = v; __syncthreads();
    for (int o = 1; o < 256; o <<= 1) {
        unsigned add = (t >= o) ? tmp[t - o] : 0u;
        __syncthreads();
        tmp[t] += add;
        __syncthreads();
    }
    off[t] = tmp[t] - v;
    if (t == 255) off[256] = tmp[t];             // total = n
}

// C: scatter points into cell-sorted SoA
__global__ void k_scatter(const float2* __restrict__ pc, const float* __restrict__ sq,
                          const int* __restrict__ cellOf, const int* __restrict__ rank,
                          const unsigned* __restrict__ cnt, const unsigned* __restrict__ off,
                          int* __restrict__ sIdx, float* __restrict__ sX,
                          float* __restrict__ sY, float* __restrict__ sSq, int n) {
    int i = blockIdx.x * blockDim.x + threadIdx.x;
    if (i >= n) return;
    int c = cellOf[i];
    unsigned pos = cnt[c] + off[c >> 8] + (unsigned)rank[i];
    sIdx[pos] = i;
    float2 p = pc[i];
    sX[pos] = p.x; sY[pos] = p.y; sSq[pos] = sq[i];
}

// D: per-query ring scan (in sorted order for wave homogeneity) + inline epilogue.
// Exact d2 formula per candidate; u64 key min = exact numpy tie semantics.
__global__ __launch_bounds__(256)
void k_query(const float2* __restrict__ pc,
             const unsigned* __restrict__ cnt, const unsigned* __restrict__ off,
             const int* __restrict__ sIdx, const float* __restrict__ sX,
             const float* __restrict__ sY, const float* __restrict__ sSq,
             float* __restrict__ out, int n) {
#pragma clang fp contract(off)
    int t = blockIdx.x * blockDim.x + threadIdx.x;
    if (t >= n) return;
    const int   i   = sIdx[t];
    const float xi  = sX[t], yi = sY[t], sqi = sSq[t];

    int cx0, cy0; cell_xy(xi, yi, cx0, cy0);

    unsigned long long bk = ~0ull;
    float bd = BIGV;

    // scan one contiguous span of sorted slots [s0,s1)
    auto scan_span = [&](unsigned s0, unsigned s1) {
        for (unsigned s = s0; s < s1; ++s) {
            float xj = sX[s], yj = sY[s], sj = sSq[s];
            float dot = fmaf(yj, yi, xj * xi);        // reference fma order
            float ssum = sqi + sj;
            float d2 = fmaf(-2.0f, dot, ssum);
            d2 = fmaxf(d2, 0.0f);
            int j = sIdx[s];
            if (j != i) {
                unsigned long long key =
                    ((unsigned long long)__float_as_uint(d2) << 32) | (unsigned)j;
                if (key < bk) { bk = key; bd = d2; }
            }
        }
    };
    // horizontal run of cells [cxlo..cxhi] in row cy == one contiguous span
    auto scan_row = [&](int cy, int cxlo, int cxhi) {
        if (cy < 0 || cy >= GDIM) return;
        cxlo = max(cxlo, 0); cxhi = min(cxhi, GDIM - 1);
        if (cxlo > cxhi) return;
        int cLo = (cy << 8) | cxlo;
        int cHi = (cy << 8) | cxhi;
        unsigned s0 = cnt[cLo] + off[cLo >> 8];
        unsigned s1 = cnt[cHi + 1] + off[(cHi + 1) >> 8];
        scan_span(s0, s1);
    };

    for (int r = 0; r < GDIM; ++r) {
        if (r == 0) {
            scan_row(cy0, cx0, cx0);
        } else {
            const int xlo = cx0 - r, xhi = cx0 + r;
            const int ylo = cy0 - r, yhi = cy0 + r;
            scan_row(ylo, xlo, xhi);                  // bottom row
            scan_row(yhi, xlo, xhi);                  // top row
            // side columns, y in (ylo, yhi) exclusive: per-cell spans
            for (int y = max(ylo + 1, 0); y <= min(yhi - 1, GDIM - 1); ++y) {
                if (xlo >= 0) scan_row(y, xlo, xlo);
                if (xhi < GDIM) scan_row(y, xhi, xhi);
            }
        }
        // after completing ring r, unscanned points are >= r*CELL away (true dist).
        // 0.01 slack >> max d2 rounding error (~1e-3) -> conservative.
        float g = (float)r * CELL;
        if (g * g > bd + 0.01f) break;
    }

    // epilogue (exact reference rounding, as validated in prior rounds)
    float esdf = sqrtf(bd);
    int ix = (int)(bk & 0xffffffffull);
    float2 pn = pc[ix];
    float dx = xi - pn.x;
    float dy = yi - pn.y;
    float a  = dx * dx;
    float c2 = dy * dy;
    float nrm = sqrtf(a + c2);
    float inv = nrm + EPSV;
    float gx = dx / inv;
    float gy = dy / inv;
    out[0 * n + i] = gx;
    out[1 * n + i] = -gx;
    out[2 * n + i] = gy;
    out[3 * n + i] = -gy;
    out[4 * n + i] = gx;
    out[5 * n + i] = gy;
    out[6 * n + i] = esdf / 10.0f;
}

extern "C" void kernel_launch(void* const* d_in, const int* in_sizes, int n_in,
                              void* d_out, int out_size, void* d_ws, size_t ws_size,
                              hipStream_t stream) {
    const float2* pc = (const float2*)d_in[0];
    float* out = (float*)d_out;
    const int n = in_sizes[0] / 2;               // 16384

    // ws carve (4B units): 7n + (NCELL+1) + 256 + 257 ~= 723 KB
    float*    sq     = (float*)d_ws;             // n
    int*      cellOf = (int*)(sq + n);           // n
    int*      rank   = cellOf + n;               // n
    int*      sIdx   = rank + n;                 // n
    float*    sX     = (float*)(sIdx + n);       // n
    float*    sY     = sX + n;                   // n
    float*    sSq    = sY + n;                   // n
    unsigned* cnt    = (unsigned*)(sSq + n);     // NCELL+1
    unsigned* sums   = cnt + NCELL + 1;          // 256
    unsigned* off    = sums + 256;               // 257

    hipMemsetAsync(cnt, 0, (NCELL + 1) * sizeof(unsigned), stream);
    k_hist   <<<(n + 255) / 256, 256, 0, stream>>>(pc, sq, cellOf, rank, cnt, n);
    k_scan1  <<<NCELL / 256, 256, 0, stream>>>(cnt, sums);
    k_scan2  <<<1, 256, 0, stream>>>(sums, off);
    k_scatter<<<(n + 255) / 256, 256, 0, stream>>>(pc, sq, cellOf, rank, cnt, off,
                                                   sIdx, sX, sY, sSq, n);
    k_query  <<<(n + 255) / 256, 256, 0, stream>>>(pc, cnt, off, sIdx, sX, sY, sSq,
                                                   out, n);
}

// Round 9
// 89.923 us; speedup vs baseline: 1.0606x; 1.0606x over previous
//
#include <hip/hip_runtime.h>
#include <math.h>

#define TPB 256          // threads per block
#define QPT 2            // queries per thread -> 512 queries per block
#define QSPAN (TPB * QPT)
#define JWIN 512         // shared j-window per block, staged in LDS SoA (6 KB)
#define BIGV 1e10f
#define EPSV 1e-8f

typedef float f32x2 __attribute__((ext_vector_type(2)));

#if __has_builtin(__builtin_elementwise_fma)
#define VFMA(a, b, c) __builtin_elementwise_fma((a), (b), (c))
#else
static __device__ __forceinline__ f32x2 VFMA(f32x2 a, f32x2 b, f32x2 c) {
    f32x2 r; r.x = fmaf(a.x, b.x, c.x); r.y = fmaf(a.y, b.y, c.y); return r;
}
#endif
#if __has_builtin(__builtin_elementwise_max)
#define VMAX(a, b) __builtin_elementwise_max((a), (b))
#define VMIN(a, b) __builtin_elementwise_min((a), (b))
#else
static __device__ __forceinline__ f32x2 VMAX(f32x2 a, f32x2 b) {
    f32x2 r; r.x = fmaxf(a.x, b.x); r.y = fmaxf(a.y, b.y); return r;
}
static __device__ __forceinline__ f32x2 VMIN(f32x2 a, f32x2 b) {
    f32x2 r; r.x = fminf(a.x, b.x); r.y = fminf(a.y, b.y); return r;
}
#endif

// kernel 1: sq[i] = x*x + y*y (reference rounding) + init packed keys
__global__ void esdf_prep(const float2* __restrict__ pc,
                          float* __restrict__ sq,
                          unsigned long long* __restrict__ key, int n) {
#pragma clang fp contract(off)
    int i = blockIdx.x * blockDim.x + threadIdx.x;
    if (i < n) {
        float2 p = pc[i];
        float xx = p.x * p.x;
        float yy = p.y * p.y;
        sq[i] = xx + yy;
        key[i] = ~0ull;
    }
}

// kernel 2: packed-FP32 scan. Per 8-j tile: v_pk math -> packed clamp ->
// SELF-PATCH (only in the one block-uniform window containing the query) ->
// packed min-tree -> single compare vs running best; rare slow path recovers
// exact lowest-j argmin. Cross-block merge: atomicMin on (d2_bits<<32)|j.
__global__ __launch_bounds__(TPB)
void esdf_nn(const float2* __restrict__ pc,
             const float* __restrict__ sq,
             unsigned long long* __restrict__ key, int n) {
#pragma clang fp contract(off)
    const int tid    = threadIdx.x;
    const int jparts = n / JWIN;                  // 32
    const int qblk   = blockIdx.x / jparts;       // 32 query blocks
    const int jpart  = blockIdx.x % jparts;
    const int qbase  = qblk * QSPAN;
    const int jbase  = jpart * JWIN;
    // QSPAN == JWIN: the self-point is in this window iff qblk == jpart
    const bool selfwin = (qblk == jpart);

    // --- stage j-window into LDS as SoA ---
    __shared__ float sXl[JWIN];
    __shared__ float sYl[JWIN];
    __shared__ float sSql[JWIN];
#pragma unroll
    for (int h = 0; h < JWIN / TPB; ++h) {
        int t = h * TPB + tid;
        float2 p = pc[jbase + t];
        sXl[t] = p.x;
        sYl[t] = p.y;
        sSql[t] = sq[jbase + t];
    }

    // per-thread query registers (static names; QPT=2)
    const int iq0 = qbase + tid;
    const int iq1 = qbase + TPB + tid;
    float2 p0 = pc[iq0], p1 = pc[iq1];
    const float x0 = p0.x, y0 = p0.y, s0 = sq[iq0];
    const float x1 = p1.x, y1 = p1.y, s1 = sq[iq1];
    __syncthreads();

    const f32x2 xv0 = {x0, x0}, yv0 = {y0, y0}, sv0 = {s0, s0};
    const f32x2 xv1 = {x1, x1}, yv1 = {y1, y1}, sv1 = {s1, s1};
    const f32x2 m2v = {-2.0f, -2.0f};
    const f32x2 zv  = {0.0f, 0.0f};

    float best0 = BIGV, best1 = BIGV;
    int   bi0 = 0, bi1 = 0;

    for (int jt = 0; jt < JWIN; jt += 8) {
        const int j0 = jbase + jt;
        // 6 ds_read_b128: 8 x's, 8 y's, 8 sq's
        float4 xA = *(const float4*)&sXl[jt];
        float4 xB = *(const float4*)&sXl[jt + 4];
        float4 yA = *(const float4*)&sYl[jt];
        float4 yB = *(const float4*)&sYl[jt + 4];
        float4 qA = *(const float4*)&sSql[jt];
        float4 qB = *(const float4*)&sSql[jt + 4];
        f32x2 xp[4] = {{xA.x, xA.y}, {xA.z, xA.w}, {xB.x, xB.y}, {xB.z, xB.w}};
        f32x2 yp[4] = {{yA.x, yA.y}, {yA.z, yA.w}, {yB.x, yB.y}, {yB.z, yB.w}};
        f32x2 sp[4] = {{qA.x, qA.y}, {qA.z, qA.w}, {qB.x, qB.y}, {qB.z, qB.w}};

        // ---- query 0 ----
        {
            f32x2 d2p[4];
#pragma unroll
            for (int p = 0; p < 4; ++p) {
                f32x2 t   = xp[p] * xv0;              // v_pk_mul_f32
                f32x2 dot = VFMA(yp[p], yv0, t);      // v_pk_fma_f32 (ref order)
                f32x2 s   = sv0 + sp[p];              // v_pk_add_f32
                f32x2 d2  = VFMA(m2v, dot, s);        // v_pk_fma_f32
                d2p[p] = VMAX(d2, zv);                // v_pk_max_f32 (ref clamp)
            }
            if (selfwin) {                            // block-uniform branch
#pragma unroll
                for (int p = 0; p < 4; ++p) {         // mirror reference +eye*BIG
                    if (j0 + 2 * p     == iq0) d2p[p].x = BIGV;
                    if (j0 + 2 * p + 1 == iq0) d2p[p].y = BIGV;
                }
            }
            f32x2 mA = VMIN(d2p[0], d2p[1]);
            f32x2 mB = VMIN(d2p[2], d2p[3]);
            f32x2 mC = VMIN(mA, mB);
            float tmin = fminf(mC.x, mC.y);
            if (tmin < best0) {                       // rare record update
                best0 = tmin;
                bool done = false;
#pragma unroll
                for (int k = 0; k < 8; ++k) {         // lowest j achieving tmin
                    float v = (k & 1) ? d2p[k >> 1].y : d2p[k >> 1].x;
                    if (!done && v == tmin) { bi0 = j0 + k; done = true; }
                }
            }
        }
        // ---- query 1 ----
        {
            f32x2 d2p[4];
#pragma unroll
            for (int p = 0; p < 4; ++p) {
                f32x2 t   = xp[p] * xv1;
                f32x2 dot = VFMA(yp[p], yv1, t);
                f32x2 s   = sv1 + sp[p];
                f32x2 d2  = VFMA(m2v, dot, s);
                d2p[p] = VMAX(d2, zv);
            }
            if (selfwin) {
#pragma unroll
                for (int p = 0; p < 4; ++p) {
                    if (j0 + 2 * p     == iq1) d2p[p].x = BIGV;
                    if (j0 + 2 * p + 1 == iq1) d2p[p].y = BIGV;
                }
            }
            f32x2 mA = VMIN(d2p[0], d2p[1]);
            f32x2 mB = VMIN(d2p[2], d2p[3]);
            f32x2 mC = VMIN(mA, mB);
            float tmin = fminf(mC.x, mC.y);
            if (tmin < best1) {
                best1 = tmin;
                bool done = false;
#pragma unroll
                for (int k = 0; k < 8; ++k) {
                    float v = (k & 1) ? d2p[k >> 1].y : d2p[k >> 1].x;
                    if (!done && v == tmin) { bi1 = j0 + k; done = true; }
                }
            }
        }
    }

    // pack (d2,j) -> u64 key; lexicographic min == numpy argmin w/ low-j ties
    unsigned long long k0 =
        ((unsigned long long)__float_as_uint(best0) << 32) | (unsigned)bi0;
    unsigned long long k1 =
        ((unsigned long long)__float_as_uint(best1) << 32) | (unsigned)bi1;
    atomicMin(&key[iq0], k0);
    atomicMin(&key[iq1], k1);
}

// kernel 3: unpack key + epilogue
__global__ void esdf_finalize(const float2* __restrict__ pc,
                              const unsigned long long* __restrict__ key,
                              float* __restrict__ out, int n) {
#pragma clang fp contract(off)
    int q = blockIdx.x * blockDim.x + threadIdx.x;
    if (q >= n) return;
    unsigned long long k = key[q];
    int   ix = (int)(k & 0xffffffffull);
    float b  = __uint_as_float((unsigned)(k >> 32));
    float esdf = sqrtf(b);
    float2 pn = pc[ix];
    float2 pq = pc[q];
    float dx = pq.x - pn.x;
    float dy = pq.y - pn.y;
    float a  = dx * dx;
    float c2 = dy * dy;
    float nrm = sqrtf(a + c2);
    float inv = nrm + EPSV;
    float gx = dx / inv;
    float gy = dy / inv;
    // out = mu(4,N) then lam(3,N), flat
    out[0 * n + q] = gx;
    out[1 * n + q] = -gx;
    out[2 * n + q] = gy;
    out[3 * n + q] = -gy;
    out[4 * n + q] = gx;
    out[5 * n + q] = gy;
    out[6 * n + q] = esdf / 10.0f;
}

extern "C" void kernel_launch(void* const* d_in, const int* in_sizes, int n_in,
                              void* d_out, int out_size, void* d_ws, size_t ws_size,
                              hipStream_t stream) {
    const float2* pc = (const float2*)d_in[0];
    float* out = (float*)d_out;
    const int n = in_sizes[0] / 2;               // 16384

    // ws layout: sq[n] f32 (64KB) | key[n] u64 (128KB)
    float* sq = (float*)d_ws;
    unsigned long long* key = (unsigned long long*)(sq + n);

    const int jparts = n / JWIN;                 // 32
    const int qblks  = n / QSPAN;                // 32

    esdf_prep<<<(n + 255) / 256, 256, 0, stream>>>(pc, sq, key, n);
    esdf_nn<<<qblks * jparts, TPB, 0, stream>>>(pc, sq, key, n);
    esdf_finalize<<<(n + 255) / 256, 256, 0, stream>>>(pc, key, out, n);
}